// Round 11
// baseline (499.762 us; speedup 1.0000x reference)
//
#include <hip/hip_runtime.h>
#include <hip/hip_fp16.h>

constexpr int N = 200000;
constexpr int E = 5000000;
constexpr int F = 16;
constexpr int CAP = 2048;        // LDS col staging per layer block
constexpr int BUCKB = 10;        // bucket = dst >> 10 (1024 nodes/bucket)
constexpr int NBKT = (N + 1023) >> 10;   // 196
constexpr int NB_CH = 512;       // chunk blocks for hist/scatter
constexpr int BANDS = 8;         // src-band radix within each node's neighbor list

// h storage: two fp16 planes, plane0 = features 0-7, plane1 = features 8-15.
// Each plane = N rows x 16 B (uint[N*4]) = 3.2 MB -> fits a 4 MB per-XCD L2.

// ---- 0: convert x to planes ----
__global__ __launch_bounds__(256) void x2h_kernel(const float* __restrict__ x,
                                                  unsigned* __restrict__ p0,
                                                  unsigned* __restrict__ p1) {
    int i = blockIdx.x * 256 + threadIdx.x;       // over N*8 feature-pairs
    if (i < N * 8) {
        int n = i >> 3, q = i & 7;
        float2 v = reinterpret_cast<const float2*>(x)[i];
        __half2 h = __floats2half2_rn(v.x, v.y);
        unsigned u = *reinterpret_cast<unsigned*>(&h);
        if (q < 4) p0[n * 4 + q] = u; else p1[n * 4 + (q - 4)] = u;
    }
}

// ---- 1: per-(bucket, block) histogram of dst ----
__global__ __launch_bounds__(1024) void hist_kernel(const int* __restrict__ dst,
                                                    int* __restrict__ hist) {
    __shared__ int h[NBKT];
    if (threadIdx.x < NBKT) h[threadIdx.x] = 0;
    __syncthreads();
    const int chunk = (E + NB_CH - 1) / NB_CH;
    const int lo = blockIdx.x * chunk, hi = min(E, lo + chunk);
    for (int e = lo + (int)threadIdx.x; e < hi; e += 1024)
        atomicAdd(&h[dst[e] >> BUCKB], 1);
    __syncthreads();
    if (threadIdx.x < NBKT)
        hist[threadIdx.x * NB_CH + blockIdx.x] = h[threadIdx.x];   // bucket-major
}

// ---- 2: exclusive scan of hist; extract bucket starts ----
__global__ __launch_bounds__(1024) void scan_hist_kernel(int* __restrict__ hist,
                                                         int* __restrict__ bstart) {
    __shared__ int sm[1024];
    const int M = NBKT * NB_CH;
    const int per = (M + 1023) / 1024;
    const int t = threadIdx.x;
    const int lo = t * per, hi = min(M, lo + per);
    int s = 0;
    for (int i = lo; i < hi; i++) s += hist[i];
    sm[t] = s; __syncthreads();
    for (int st = 1; st < 1024; st <<= 1) {
        int v = (t >= st) ? sm[t - st] : 0;
        __syncthreads();
        sm[t] += v;
        __syncthreads();
    }
    int run = sm[t] - s;
    for (int i = lo; i < hi; i++) { int v = hist[i]; hist[i] = run; run += v; }
    __syncthreads();
    if (t <= NBKT) bstart[t] = (t < NBKT) ? hist[t * NB_CH] : E;
}

// ---- 3: scatter packed (local_dst<<18 | src) into bucket-major order ----
__global__ __launch_bounds__(1024) void bucket_scatter_kernel(const int* __restrict__ src,
                                                              const int* __restrict__ dst,
                                                              const int* __restrict__ hist,
                                                              unsigned* __restrict__ pairs) {
    __shared__ int cur[NBKT];
    if (threadIdx.x < NBKT) cur[threadIdx.x] = hist[threadIdx.x * NB_CH + blockIdx.x];
    __syncthreads();
    const int chunk = (E + NB_CH - 1) / NB_CH;
    const int lo = blockIdx.x * chunk, hi = min(E, lo + chunk);
    for (int e = lo + (int)threadIdx.x; e < hi; e += 1024) {
        int d = dst[e];
        int p = atomicAdd(&cur[d >> BUCKB], 1);
        pairs[p] = ((unsigned)(d & 1023) << 18) | (unsigned)src[e];
    }
}

// ---- 4: per-bucket CSR with src-band radix: key = (local_dst<<3)|(src>>15) ----
__global__ __launch_bounds__(256) void build_csr_kernel(const unsigned* __restrict__ pairs,
                                                        const int* __restrict__ bstart,
                                                        int* __restrict__ off,
                                                        int* __restrict__ col) {
    __shared__ int cnt[1024 * BANDS];             // 32 KB
    __shared__ int sm[256];
    const int b = blockIdx.x;
    const int p0 = bstart[b], p1 = bstart[b + 1];
    const int nodeBase = b << BUCKB;
    const int t = threadIdx.x;
    for (int i = t; i < 1024 * BANDS; i += 256) cnt[i] = 0;
    __syncthreads();
    for (int j = p0 + t; j < p1; j += 256) {
        unsigned pk = pairs[j];
        int key = (int)(pk >> 18) * BANDS + (int)((pk & 0x3FFFF) >> 15);
        atomicAdd(&cnt[key], 1);
    }
    __syncthreads();
    int loc[32];
    int s = 0;
#pragma unroll
    for (int q = 0; q < 32; q++) { loc[q] = cnt[32 * t + q]; s += loc[q]; }
    sm[t] = s; __syncthreads();
    for (int st = 1; st < 256; st <<= 1) {
        int v = (t >= st) ? sm[t - st] : 0;
        __syncthreads();
        sm[t] += v;
        __syncthreads();
    }
    int run = p0 + sm[t] - s;
#pragma unroll
    for (int q = 0; q < 32; q++) { cnt[32 * t + q] = run; run += loc[q]; }
    __syncthreads();
    const int n0 = nodeBase + 4 * t;
#pragma unroll
    for (int q = 0; q < 4; q++)
        if (n0 + q < N) off[n0 + q] = cnt[(4 * t + q) * BANDS];
    if (b == gridDim.x - 1 && t == 255) off[N] = p1;
    __syncthreads();
    for (int j = p0 + t; j < p1; j += 256) {
        unsigned pk = pairs[j];
        int srcv = (int)(pk & 0x3FFFF);
        int key = (int)(pk >> 18) * BANDS + (srcv >> 15);
        int p = atomicAdd(&cnt[key], 1);
        col[p] = srcv;
    }
}

// ---- fused gather + SAGE update, split-plane two-pass gather ----
// block = 256 threads = 16 nodes x 16 lanes; lane j walks edges j, j+16, ...
// loading full 16B plane rows; shfl-tree reduce. Cols staged once, reused by
// both passes. Device-wide working set per pass = one 3.2MB plane (L2-resident).
// NOTE: no nontemporal ops anywhere -- nt load/store scope bits can bypass a
// dirty L2 line and read/expose stale data across kernels (round-10 failure).
__global__ __launch_bounds__(256) void layer_kernel(
    const unsigned* __restrict__ hin0, const unsigned* __restrict__ hin1,
    unsigned* __restrict__ hout0, unsigned* __restrict__ hout1,
    const int* __restrict__ off, const int* __restrict__ col,
    const float* __restrict__ Wl, const float* __restrict__ bl,
    const float* __restrict__ Wr,
    const float* __restrict__ fcW, const float* __restrict__ fcb,
    int mode,                 // 0 = plain, 1 = +fc1+relu, 2 = final (slice8+fc2+relu+softmax)
    float* __restrict__ outp) {
    __shared__ int cols[CAP];
    __shared__ float Mt[16][17], Xt[16][17];
    const int tid = threadIdx.x;
    const int nb = blockIdx.x * 16;
    const int base = off[nb];
    const int tot = off[nb + 16] - base;
    const int stot = min(tot, CAP);
    for (int j = tid; j < stot; j += 256)           // coalesced stage of block's col range
        cols[j] = col[base + j];
    __syncthreads();

    const int ty   = tid >> 4;    // group = node (16 lanes, within one wave)
    const int lane = tid & 15;
    const int n  = nb + ty;
    const int o0 = off[n] - base, o1 = off[n + 1] - base;
    const int lim = min(o1, CAP);
    const float inv = 1.f / fmaxf((float)(o1 - o0), 1.f);

#pragma unroll
    for (int p = 0; p < 2; p++) {
        const unsigned* __restrict__ plane = p ? hin1 : hin0;
        float a0 = 0, a1 = 0, a2 = 0, a3 = 0, a4 = 0, a5 = 0, a6 = 0, a7 = 0;
        int j = o0 + lane;
        for (; j < lim; j += 16) {
            int c = cols[j];
            uint4 u = *reinterpret_cast<const uint4*>(&plane[c * 4]);
            float2 f0 = __half22float2(*reinterpret_cast<__half2*>(&u.x));
            float2 f1 = __half22float2(*reinterpret_cast<__half2*>(&u.y));
            float2 f2 = __half22float2(*reinterpret_cast<__half2*>(&u.z));
            float2 f3 = __half22float2(*reinterpret_cast<__half2*>(&u.w));
            a0 += f0.x; a1 += f0.y; a2 += f1.x; a3 += f1.y;
            a4 += f2.x; a5 += f2.y; a6 += f3.x; a7 += f3.y;
        }
        for (; j < o1; j += 16) {                   // CAP-overflow fallback (rare)
            int c = col[base + j];
            uint4 u = *reinterpret_cast<const uint4*>(&plane[c * 4]);
            float2 f0 = __half22float2(*reinterpret_cast<__half2*>(&u.x));
            float2 f1 = __half22float2(*reinterpret_cast<__half2*>(&u.y));
            float2 f2 = __half22float2(*reinterpret_cast<__half2*>(&u.z));
            float2 f3 = __half22float2(*reinterpret_cast<__half2*>(&u.w));
            a0 += f0.x; a1 += f0.y; a2 += f1.x; a3 += f1.y;
            a4 += f2.x; a5 += f2.y; a6 += f3.x; a7 += f3.y;
        }
#pragma unroll
        for (int st = 1; st < 16; st <<= 1) {
            a0 += __shfl_xor(a0, st); a1 += __shfl_xor(a1, st);
            a2 += __shfl_xor(a2, st); a3 += __shfl_xor(a3, st);
            a4 += __shfl_xor(a4, st); a5 += __shfl_xor(a5, st);
            a6 += __shfl_xor(a6, st); a7 += __shfl_xor(a7, st);
        }
        if (lane == 0) {
            Mt[ty][p * 8 + 0] = a0 * inv; Mt[ty][p * 8 + 1] = a1 * inv;
            Mt[ty][p * 8 + 2] = a2 * inv; Mt[ty][p * 8 + 3] = a3 * inv;
            Mt[ty][p * 8 + 4] = a4 * inv; Mt[ty][p * 8 + 5] = a5 * inv;
            Mt[ty][p * 8 + 6] = a6 * inv; Mt[ty][p * 8 + 7] = a7 * inv;
        }
    }
    // self row
    {
        const __half* h0 = (const __half*)hin0;
        const __half* h1 = (const __half*)hin1;
        Xt[ty][lane] = (lane < 8) ? __half2float(h0[n * 8 + lane])
                                  : __half2float(h1[n * 8 + (lane - 8)]);
    }
    __syncthreads();

    const int k = lane;
    float a = bl[k];
#pragma unroll
    for (int kk = 0; kk < F; kk++)
        a = fmaf(Mt[ty][kk], Wl[k * F + kk], fmaf(Xt[ty][kk], Wr[k * F + kk], a));
    float o = fmaxf(a, 0.f);   // relu follows every SAGE layer in this graph

    if (mode == 2) {
        __syncthreads();
        Mt[ty][k] = o;
        __syncthreads();
        if (k < 8) {           // slice [:, :8] -> fc2 (8x8) -> relu -> softmax over 8
            float a2f = fcb[k];
#pragma unroll
            for (int kk = 0; kk < 8; kk++) a2f = fmaf(Mt[ty][kk], fcW[k * 8 + kk], a2f);
            float u = fmaxf(a2f, 0.f);
            float mx = u;
            mx = fmaxf(mx, __shfl_xor(mx, 1));
            mx = fmaxf(mx, __shfl_xor(mx, 2));
            mx = fmaxf(mx, __shfl_xor(mx, 4));
            float ex = __expf(u - mx);
            float sum = ex;
            sum += __shfl_xor(sum, 1);
            sum += __shfl_xor(sum, 2);
            sum += __shfl_xor(sum, 4);
            outp[n * 8 + k] = ex / sum;
        }
        return;
    }

    if (mode == 1) {
        __syncthreads();
        Mt[ty][k] = o;
        __syncthreads();
        float a2f = fcb[k];
#pragma unroll
        for (int kk = 0; kk < F; kk++) a2f = fmaf(Mt[ty][kk], fcW[k * F + kk], a2f);
        o = fmaxf(a2f, 0.f);
    }

    // pack outputs to planes (modes 0 and 1)
    __syncthreads();
    Mt[ty][k] = o;
    __syncthreads();
    if (k < 8) {
        __half2 hp = __floats2half2_rn(Mt[ty][2 * k], Mt[ty][2 * k + 1]);
        unsigned u = *reinterpret_cast<unsigned*>(&hp);
        if (k < 4) hout0[n * 4 + k] = u;
        else       hout1[n * 4 + (k - 4)] = u;
    }
}

extern "C" void kernel_launch(void* const* d_in, const int* in_sizes, int n_in,
                              void* d_out, int out_size, void* d_ws, size_t ws_size,
                              hipStream_t stream) {
    const float* x = (const float*)d_in[0];
    const int* edge = (const int*)d_in[1];   // int64 inputs arrive as int32
    const int* src = edge;
    const int* dst = edge + E;
    const float* c1_Wl = (const float*)d_in[2];
    const float* c1_bl = (const float*)d_in[3];
    const float* c1_Wr = (const float*)d_in[4];
    const float* c2_Wl = (const float*)d_in[5];
    const float* c2_bl = (const float*)d_in[6];
    const float* c2_Wr = (const float*)d_in[7];
    const float* fc1_W = (const float*)d_in[8];
    const float* fc1_b = (const float*)d_in[9];
    const float* fc2_W = (const float*)d_in[10];
    const float* fc2_b = (const float*)d_in[11];
    float* out = (float*)d_out;

    // workspace: pairs 20MB + col 20MB + off + hist ~0.4MB + 6 planes x 3.2MB  (~60MB)
    char* w = (char*)d_ws;
    unsigned* pairs = (unsigned*)w;    w += (size_t)E * 4;
    int* col  = (int*)w;               w += (size_t)E * 4;
    int* off  = (int*)w;               w += (size_t)(N + 4) * 4;
    int* hist = (int*)w;               w += (size_t)NBKT * NB_CH * 4;
    int* bstart = (int*)w;             w += (size_t)(NBKT + 4) * 4;
    unsigned* xp0 = (unsigned*)w;      w += (size_t)N * 4 * 4;
    unsigned* xp1 = (unsigned*)w;      w += (size_t)N * 4 * 4;
    unsigned* hA0 = (unsigned*)w;      w += (size_t)N * 4 * 4;
    unsigned* hA1 = (unsigned*)w;      w += (size_t)N * 4 * 4;
    unsigned* hB0 = (unsigned*)w;      w += (size_t)N * 4 * 4;
    unsigned* hB1 = (unsigned*)w;      w += (size_t)N * 4 * 4;

    const int nblk_nodes = N / 16;                   // 12500

    // ---- CSR build (bucket counting sort) + x plane convert ----
    x2h_kernel<<<(N * 8 + 255) / 256, 256, 0, stream>>>(x, xp0, xp1);
    hist_kernel<<<NB_CH, 1024, 0, stream>>>(dst, hist);
    scan_hist_kernel<<<1, 1024, 0, stream>>>(hist, bstart);
    bucket_scatter_kernel<<<NB_CH, 1024, 0, stream>>>(src, dst, hist, pairs);
    build_csr_kernel<<<NBKT, 256, 0, stream>>>(pairs, bstart, off, col);

    // ---- 4 fused layers (ping-pong plane pairs) ----
    layer_kernel<<<nblk_nodes, 256, 0, stream>>>(xp0, xp1, hA0, hA1, off, col,
        c1_Wl, c1_bl, c1_Wr, nullptr, nullptr, 0, nullptr);
    layer_kernel<<<nblk_nodes, 256, 0, stream>>>(hA0, hA1, hB0, hB1, off, col,
        c1_Wl + F * F, c1_bl + F, c1_Wr + F * F, fc1_W, fc1_b, 1, nullptr);
    layer_kernel<<<nblk_nodes, 256, 0, stream>>>(hB0, hB1, hA0, hA1, off, col,
        c2_Wl, c2_bl, c2_Wr, nullptr, nullptr, 0, nullptr);
    layer_kernel<<<nblk_nodes, 256, 0, stream>>>(hA0, hA1, nullptr, nullptr, off, col,
        c2_Wl + F * F, c2_bl + F, c2_Wr + F * F, fc2_W, fc2_b, 2, out);
}